// Round 9
// baseline (120.784 us; speedup 1.0000x reference)
//
#include <hip/hip_runtime.h>
#include <math.h>

#define NN 256
#define DD 128

typedef float4 f4;

#define FMA4(acc, s, v)                          \
  acc.x = fmaf(s, v.x, acc.x);                   \
  acc.y = fmaf(s, v.y, acc.y);                   \
  acc.z = fmaf(s, v.z, acc.z);                   \
  acc.w = fmaf(s, v.w, acc.w);

#define FMA4R(acc, a, p, v)                              \
  acc.x = fmaf(a, fmaxf(p.x + v.x, 0.f), acc.x);         \
  acc.y = fmaf(a, fmaxf(p.y + v.y, 0.f), acc.y);         \
  acc.z = fmaf(a, fmaxf(p.z + v.z, 0.f), acc.z);         \
  acc.w = fmaf(a, fmaxf(p.w + v.w, 0.f), acc.w);

#define ZERO4 {0.f, 0.f, 0.f, 0.f}

// Stage 128 KB global -> LDS via global_load_lds width=16 (no VGPR round-trip).
// 512 threads = 8 waves; each wave issues 16 x 1KB chunks.
__device__ __forceinline__ void stage_128k(const float* __restrict__ g,
                                           float* l, int tid) {
    const int wave = tid >> 6, lane = tid & 63;
    #pragma unroll
    for (int k = 0; k < 16; ++k) {
        const int chunk = wave * 16 + k;              // 0..127, 1 KB each
        __builtin_amdgcn_global_load_lds(
            (__attribute__((address_space(1))) void*)(void*)(g + chunk * 256 + lane * 4),
            (__attribute__((address_space(3))) void*)(l + chunk * 256),
            16, 0, 0);
    }
}

// ---------------------------------------------------------------------------
// h1_kernel: identical to round-7 version.
// ---------------------------------------------------------------------------
__global__ __launch_bounds__(512, 2) void h1_kernel(
    const float* __restrict__ emb,   // [1024][128]
    const float* __restrict__ mW1,   // [256][128]
    const float* __restrict__ mb1,   // [128]
    float* __restrict__ H1a,
    float* __restrict__ H1b)
{
    const int tid  = threadIdx.x;
    const int row0 = blockIdx.x * 4;

    __shared__ float WL[32768];      // 128 KB: mW1; later overlaid by red (32 KB)
    __shared__ f4 embT[DD];          // 2 KB : embT[k] = emb[row0+0..3][k]

    const int rs = tid >> 7, ks = tid & 127;
    const float ev = emb[(size_t)(row0 + rs) * DD + ks];
    stage_128k(mW1, WL, tid);
    ((float*)embT)[ks * 4 + rs] = ev;
    __syncthreads();

    const int oq  = tid & 63;
    const int kh  = tid >> 6;
    const int wq  = oq & 31;
    const int wr0 = (oq < 32) ? 0 : DD;
    const f4* __restrict__ WL4 = (const f4*)WL;

    f4 a0 = ZERO4, a1 = ZERO4, a2 = ZERO4, a3 = ZERO4;
    #pragma unroll
    for (int t = 0; t < 16; ++t) {
        const int k = kh * 16 + t;
        const f4 w  = WL4[(wr0 + k) * 32 + wq];
        const f4 e4 = embT[k];
        FMA4(a0, e4.x, w);
        FMA4(a1, e4.y, w);
        FMA4(a2, e4.z, w);
        FMA4(a3, e4.w, w);
    }
    __syncthreads();

    f4* red4 = (f4*)WL;
    red4[(kh * 4 + 0) * 64 + oq] = a0;
    red4[(kh * 4 + 1) * 64 + oq] = a1;
    red4[(kh * 4 + 2) * 64 + oq] = a2;
    red4[(kh * 4 + 3) * 64 + oq] = a3;
    __syncthreads();

    const float* __restrict__ redF = (const float*)WL;
    #pragma unroll
    for (int t = 0; t < 2; ++t) {
        const int o  = t * 512 + tid;
        const int rr = o >> 8, oc = o & 255;
        float v = 0.f;
        #pragma unroll
        for (int q = 0; q < 8; ++q) v += redF[(q * 4 + rr) * 256 + oc];
        if (oc < DD) H1a[(size_t)(row0 + rr) * DD + oc]        = v + mb1[oc];
        else         H1b[(size_t)(row0 + rr) * DD + (oc - DD)] = v;
    }
}

// ---------------------------------------------------------------------------
// gnn_kernel: identical to round-7 version.
// ---------------------------------------------------------------------------
__global__ __launch_bounds__(512, 2) void gnn_kernel(
    const float* __restrict__ emb,
    const float* __restrict__ coords,  // [B][256][3]
    const float* __restrict__ mW2, const float* __restrict__ mb2,
    const float* __restrict__ uW1, const float* __restrict__ ub1,
    const float* __restrict__ uW2, const float* __restrict__ ub2,
    const float* __restrict__ H1a, const float* __restrict__ H1b,
    float* __restrict__ out)
{
    const int tid  = threadIdx.x;
    const int row0 = blockIdx.x * 4;
    const int b    = row0 >> 8;
    const int i0   = row0 & 255;

    __shared__ float HbL[32768];       // 128 KB: H1b[b]; red overlays after J
    __shared__ float cS[NN * 3];
    __shared__ f4 As4[NN];
    __shared__ f4 R_T[DD];
    __shared__ f4 U_T[DD + 3];
    __shared__ f4 h_T[DD];
    __shared__ f4 sAs4[16];
    __shared__ float sAtot[4];

    const int eq = tid & 31;
    const int js = tid >> 5;

    const f4* __restrict__ Ha4 = (const f4*)(H1a + (size_t)row0 * DD);
    const f4 pa0 = Ha4[0 * 32 + eq];
    const f4 pa1 = Ha4[1 * 32 + eq];
    const f4 pa2 = Ha4[2 * 32 + eq];
    const f4 pa3 = Ha4[3 * 32 + eq];
    const int rr2 = tid >> 7, ea = tid & 127;
    const float embv = emb[(size_t)(row0 + rr2) * DD + ea];
    const float mb2v = mb2[ea], ub1v = ub1[ea], ub2v = ub2[ea];
    const float* __restrict__ cb = coords + (size_t)b * NN * 3;
    f4 cldv = ZERO4;
    if (tid < 192) cldv = ((const f4*)cb)[tid];

    stage_128k(H1b + (size_t)b * NN * DD, HbL, tid);
    if (tid < 192) ((f4*)cS)[tid] = cldv;
    __syncthreads();

    {   const int j = tid & 255, rA = tid >> 8;
        const float cjx = cS[j * 3], cjy = cS[j * 3 + 1], cjz = cS[j * 3 + 2];
        float* __restrict__ AsF = (float*)As4;
        {   const int ii = i0 + rA;
            const float dx = cjx - cS[ii * 3], dy = cjy - cS[ii * 3 + 1], dz = cjz - cS[ii * 3 + 2];
            AsF[j * 4 + rA] = __expf(-0.5f * (dx * dx + dy * dy + dz * dz)); }
        {   const int ii = i0 + rA + 2;
            const float dx = cjx - cS[ii * 3], dy = cjy - cS[ii * 3 + 1], dz = cjz - cS[ii * 3 + 2];
            AsF[j * 4 + rA + 2] = __expf(-0.5f * (dx * dx + dy * dy + dz * dz)); }
    }
    __syncthreads();

    const f4* __restrict__ Hb4 = (const f4*)HbL;
    f4 a0 = ZERO4, a1 = ZERO4, a2 = ZERO4, a3 = ZERO4, sA4 = ZERO4;
    #pragma unroll
    for (int t = 0; t < 16; ++t) {
        const int j = js * 16 + t;
        const f4 a = As4[j];
        const f4 v = Hb4[j * 32 + eq];
        sA4.x += a.x; sA4.y += a.y; sA4.z += a.z; sA4.w += a.w;
        FMA4R(a0, a.x, pa0, v);
        FMA4R(a1, a.y, pa1, v);
        FMA4R(a2, a.z, pa2, v);
        FMA4R(a3, a.w, pa3, v);
    }
    __syncthreads();

    f4* red4 = (f4*)HbL;
    red4[(js * 4 + 0) * 32 + eq] = a0;
    red4[(js * 4 + 1) * 32 + eq] = a1;
    red4[(js * 4 + 2) * 32 + eq] = a2;
    red4[(js * 4 + 3) * 32 + eq] = a3;
    if (eq == 0) sAs4[js] = sA4;
    const int kh = js, cq = eq;
    f4 wv[8];
    {   const f4* __restrict__ W2g = (const f4*)mW2;
        #pragma unroll
        for (int t = 0; t < 8; ++t) wv[t] = W2g[(size_t)(kh * 8 + t) * 32 + cq];
    }
    __syncthreads();

    const float* __restrict__ redF = (const float*)HbL;
    {   const int r = tid >> 7, e = tid & 127;
        float s = 0.f;
        #pragma unroll
        for (int q = 0; q < 16; ++q) s += redF[(q * 4 + r) * 128 + e];
        ((float*)R_T)[e * 4 + r] = s;
    }
    if (tid < 4) {
        const float* __restrict__ sF = (const float*)sAs4;
        float s = 0.f;
        #pragma unroll
        for (int q = 0; q < 16; ++q) s += sF[q * 4 + tid];
        sAtot[tid] = s;
    }
    __syncthreads();

    {   f4 g0 = ZERO4, g1 = ZERO4, g2 = ZERO4, g3 = ZERO4;
        #pragma unroll
        for (int t = 0; t < 8; ++t) {
            const f4 rv = R_T[kh * 8 + t];
            FMA4(g0, rv.x, wv[t]);
            FMA4(g1, rv.y, wv[t]);
            FMA4(g2, rv.z, wv[t]);
            FMA4(g3, rv.w, wv[t]);
        }
        red4[(kh * 4 + 0) * 32 + cq] = g0;
        red4[(kh * 4 + 1) * 32 + cq] = g1;
        red4[(kh * 4 + 2) * 32 + cq] = g2;
        red4[(kh * 4 + 3) * 32 + cq] = g3;
    }
    f4 wt0 = ZERO4, wt1 = ZERO4, wt2 = ZERO4;
    {   const f4* __restrict__ U1g = (const f4*)uW1;
        #pragma unroll
        for (int t = 0; t < 8; ++t) wv[t] = U1g[(size_t)(kh * 8 + t) * 32 + cq];
        if (kh == 15) {
            wt0 = U1g[(size_t)(DD + 0) * 32 + cq];
            wt1 = U1g[(size_t)(DD + 1) * 32 + cq];
            wt2 = U1g[(size_t)(DD + 2) * 32 + cq];
        }
    }
    __syncthreads();

    {   const int r = tid >> 7, e = tid & 127;
        float s = sAtot[r] * mb2v;
        #pragma unroll
        for (int q = 0; q < 16; ++q) s += redF[(q * 4 + r) * 128 + e];
        ((float*)U_T)[e * 4 + r] = s;
    }
    if (tid < 12) {
        const int r = tid & 3, c = tid >> 2;
        ((float*)U_T)[(DD + c) * 4 + r] = cS[(i0 + r) * 3 + c];
    }
    __syncthreads();

    {   f4 g0 = ZERO4, g1 = ZERO4, g2 = ZERO4, g3 = ZERO4;
        #pragma unroll
        for (int t = 0; t < 8; ++t) {
            const f4 uv = U_T[kh * 8 + t];
            FMA4(g0, uv.x, wv[t]);
            FMA4(g1, uv.y, wv[t]);
            FMA4(g2, uv.z, wv[t]);
            FMA4(g3, uv.w, wv[t]);
        }
        if (kh == 15) {
            const f4 uv0 = U_T[DD + 0], uv1 = U_T[DD + 1], uv2 = U_T[DD + 2];
            FMA4(g0, uv0.x, wt0); FMA4(g1, uv0.y, wt0); FMA4(g2, uv0.z, wt0); FMA4(g3, uv0.w, wt0);
            FMA4(g0, uv1.x, wt1); FMA4(g1, uv1.y, wt1); FMA4(g2, uv1.z, wt1); FMA4(g3, uv1.w, wt1);
            FMA4(g0, uv2.x, wt2); FMA4(g1, uv2.y, wt2); FMA4(g2, uv2.z, wt2); FMA4(g3, uv2.w, wt2);
        }
        red4[(kh * 4 + 0) * 32 + cq] = g0;
        red4[(kh * 4 + 1) * 32 + cq] = g1;
        red4[(kh * 4 + 2) * 32 + cq] = g2;
        red4[(kh * 4 + 3) * 32 + cq] = g3;
    }
    {   const f4* __restrict__ U2g = (const f4*)uW2;
        #pragma unroll
        for (int t = 0; t < 8; ++t) wv[t] = U2g[(size_t)(kh * 8 + t) * 32 + cq];
    }
    __syncthreads();

    {   const int r = tid >> 7, e = tid & 127;
        float s = ub1v;
        #pragma unroll
        for (int q = 0; q < 16; ++q) s += redF[(q * 4 + r) * 128 + e];
        ((float*)h_T)[e * 4 + r] = fmaxf(s, 0.f);
    }
    __syncthreads();

    {   f4 g0 = ZERO4, g1 = ZERO4, g2 = ZERO4, g3 = ZERO4;
        #pragma unroll
        for (int t = 0; t < 8; ++t) {
            const f4 hv = h_T[kh * 8 + t];
            FMA4(g0, hv.x, wv[t]);
            FMA4(g1, hv.y, wv[t]);
            FMA4(g2, hv.z, wv[t]);
            FMA4(g3, hv.w, wv[t]);
        }
        red4[(kh * 4 + 0) * 32 + cq] = g0;
        red4[(kh * 4 + 1) * 32 + cq] = g1;
        red4[(kh * 4 + 2) * 32 + cq] = g2;
        red4[(kh * 4 + 3) * 32 + cq] = g3;
    }
    __syncthreads();

    {   const int r = tid >> 7, e = tid & 127;
        float s = ub2v;
        #pragma unroll
        for (int q = 0; q < 16; ++q) s += redF[(q * 4 + r) * 128 + e];
        out[(size_t)(row0 + r) * DD + e] = embv + s;
    }
}

extern "C" void kernel_launch(void* const* d_in, const int* in_sizes, int n_in,
                              void* d_out, int out_size, void* d_ws, size_t ws_size,
                              hipStream_t stream) {
    const float* emb    = (const float*)d_in[0];
    const float* coords = (const float*)d_in[1];
    const float* mW1    = (const float*)d_in[2];
    const float* mb1    = (const float*)d_in[3];
    const float* mW2    = (const float*)d_in[4];
    const float* mb2    = (const float*)d_in[5];
    const float* uW1    = (const float*)d_in[6];
    const float* ub1    = (const float*)d_in[7];
    const float* uW2    = (const float*)d_in[8];
    const float* ub2    = (const float*)d_in[9];
    float* out = (float*)d_out;

    float* H1a = (float*)d_ws;
    float* H1b = H1a + 4 * NN * DD;

    // DIAGNOSTIC ROUND: h1 x2, gnn x4 (all idempotent; same work every call).
    // dur8 = F + 2*h1 + 4*gnn; with R7 (F + h1 + gnn = 86.5) solves h1, gnn.
    h1_kernel<<<dim3(256), dim3(512), 0, stream>>>(emb, mW1, mb1, H1a, H1b);
    h1_kernel<<<dim3(256), dim3(512), 0, stream>>>(emb, mW1, mb1, H1a, H1b);
    gnn_kernel<<<dim3(256), dim3(512), 0, stream>>>(
        emb, coords, mW2, mb2, uW1, ub1, uW2, ub2, H1a, H1b, out);
    gnn_kernel<<<dim3(256), dim3(512), 0, stream>>>(
        emb, coords, mW2, mb2, uW1, ub1, uW2, ub2, H1a, H1b, out);
    gnn_kernel<<<dim3(256), dim3(512), 0, stream>>>(
        emb, coords, mW2, mb2, uW1, ub1, uW2, ub2, H1a, H1b, out);
    gnn_kernel<<<dim3(256), dim3(512), 0, stream>>>(
        emb, coords, mW2, mb2, uW1, ub1, uW2, ub2, H1a, H1b, out);
}

// Round 12
// 108.366 us; speedup vs baseline: 1.1146x; 1.1146x over previous
//
#include <hip/hip_runtime.h>
#include <math.h>

#define NN 256
#define DD 128

typedef float4 f4;

#define FMA4(acc, s, v)                          \
  acc.x = fmaf(s, v.x, acc.x);                   \
  acc.y = fmaf(s, v.y, acc.y);                   \
  acc.z = fmaf(s, v.z, acc.z);                   \
  acc.w = fmaf(s, v.w, acc.w);

#define FMA4R(acc, a, p, v)                              \
  acc.x = fmaf(a, fmaxf(p.x + v.x, 0.f), acc.x);         \
  acc.y = fmaf(a, fmaxf(p.y + v.y, 0.f), acc.y);         \
  acc.z = fmaf(a, fmaxf(p.z + v.z, 0.f), acc.z);         \
  acc.w = fmaf(a, fmaxf(p.w + v.w, 0.f), acc.w);

#define ZERO4 {0.f, 0.f, 0.f, 0.f}

#define AS1 __attribute__((address_space(1)))
#define AS3 __attribute__((address_space(3)))

// ---------------------------------------------------------------------------
// Single fused kernel, NO workspace use. 256 blocks x 256 threads (1 block/CU,
// 4 waves). Block g owns output rows 4g..4g+3 of batch b = g>>6.
// Phase 1: recompute H1b[b] = emb[b] @ W1b IN-BLOCK (k-chunked, LDS-staged,
//          reg-tiled 8 rows x 4 spread f4-cols) -> drain-immune VALU/LDS work.
// Phase 2: pa = emb[own 4 rows]@W1a + mb1 via global GEMV (waves 0-1) while
//          waves 2-3 compute the A matrix.
// Phase 3: v7-proven post-phase: A-weighted relu j-sum, 3 GEMVs, residual.
// ---------------------------------------------------------------------------
__global__ __launch_bounds__(256, 1) void fused_gnn(
    const float* __restrict__ emb,
    const float* __restrict__ coords,
    const float* __restrict__ mW1, const float* __restrict__ mb1,
    const float* __restrict__ mW2, const float* __restrict__ mb2,
    const float* __restrict__ uW1, const float* __restrict__ ub1,
    const float* __restrict__ uW2, const float* __restrict__ ub2,
    float* __restrict__ out)
{
    const int tid  = threadIdx.x;
    const int row0 = blockIdx.x * 4;
    const int b    = row0 >> 8;
    const int i0   = row0 & 255;

    // BIG (128 KB): [0..16384) embT chunk [64][256]; [16384..24576) W1b chunk0;
    // [24576..32768) W1b chunk1. After recompute: H1bL[256][32] f4 over all of
    // it; red4 (16 KB) overlays the front after the j-phase.
    __shared__ float BIG[32768];
    __shared__ float cS[NN * 3];       // 3 KB
    __shared__ f4 As4[NN];             // 4 KB : As4[j] = A[0..3][j]
    __shared__ float paS[4 * DD];      // 2 KB : H1a own rows + mb1
    __shared__ f4 R_T[DD];             // 2 KB
    __shared__ f4 U_T[DD + 3];
    __shared__ f4 h_T[DD];
    __shared__ f4 sAs4[8];
    __shared__ float sAtot[4];

    float* embT  = BIG;                // [64][256] (k-local, row)
    float* W1bC0 = BIG + 16384;        // [64][128]
    float* W1bC1 = BIG + 24576;

    const f4* __restrict__ emb4 = (const f4*)emb;
    const f4* __restrict__ mW14 = (const f4*)mW1;

    // ---- stage coords ----
    if (tid < 192) ((f4*)cS)[tid] = ((const f4*)(coords + (size_t)b * NN * 3))[tid];

    // ---- issue emb chunk0 reads (transposed write below) ----
    const int a_ = tid >> 4, b_ = tid & 15;
    f4 ev[16];
    #pragma unroll
    for (int i = 0; i < 16; ++i)
        ev[i] = emb4[(size_t)(b * NN + (b_ + 16 * i)) * 32 + a_];          // chunk0: cf = a_

    // ---- stage BOTH W1b chunks via global_load_lds (linear, 32 KB each) ----
    {
        const float* g0 = mW1 + (size_t)(DD + 0) * DD;        // W1b rows 0..63
        const float* g1 = mW1 + (size_t)(DD + 64) * DD;       // W1b rows 64..127
        const int wave = tid >> 6, lane = tid & 63;
        #pragma unroll
        for (int k = 0; k < 8; ++k) {
            const int c = wave * 8 + k;                       // 0..31, 1 KB each
            __builtin_amdgcn_global_load_lds((AS1 void*)(void*)(g0 + c * 256 + lane * 4),
                                             (AS3 void*)(W1bC0 + c * 256), 16, 0, 0);
        }
        #pragma unroll
        for (int k = 0; k < 8; ++k) {
            const int c = wave * 8 + k;
            __builtin_amdgcn_global_load_lds((AS1 void*)(void*)(g1 + c * 256 + lane * 4),
                                             (AS3 void*)(W1bC1 + c * 256), 16, 0, 0);
        }
    }

    // ---- transpose-write emb chunk0 into embT ----
    #pragma unroll
    for (int i = 0; i < 16; ++i) {
        const int row = b_ + 16 * i;
        embT[(4 * a_ + 0) * 256 + row] = ev[i].x;
        embT[(4 * a_ + 1) * 256 + row] = ev[i].y;
        embT[(4 * a_ + 2) * 256 + row] = ev[i].z;
        embT[(4 * a_ + 3) * 256 + row] = ev[i].w;
    }
    __syncthreads();

    // ---- pa GEMV (waves 0-1) || A-matrix (waves 2-3) ----
    if (tid < 128) {
        const int rr = tid >> 5, cq = tid & 31;
        f4 acc = ZERO4;
        const f4* __restrict__ erow = emb4 + (size_t)(row0 + rr) * 32;
        #pragma unroll 8
        for (int kq = 0; kq < 32; ++kq) {
            const f4 e  = erow[kq];
            const f4 w0 = mW14[(size_t)(4 * kq + 0) * 32 + cq];
            const f4 w1 = mW14[(size_t)(4 * kq + 1) * 32 + cq];
            const f4 w2 = mW14[(size_t)(4 * kq + 2) * 32 + cq];
            const f4 w3 = mW14[(size_t)(4 * kq + 3) * 32 + cq];
            FMA4(acc, e.x, w0);
            FMA4(acc, e.y, w1);
            FMA4(acc, e.z, w2);
            FMA4(acc, e.w, w3);
        }
        const f4 mb = ((const f4*)mb1)[cq];
        acc.x += mb.x; acc.y += mb.y; acc.z += mb.z; acc.w += mb.w;
        ((f4*)paS)[rr * 32 + cq] = acc;
    } else {
        const int t2 = tid - 128;
        #pragma unroll
        for (int u = 0; u < 2; ++u) {
            const int jj = 2 * t2 + u;
            const float cjx = cS[jj * 3], cjy = cS[jj * 3 + 1], cjz = cS[jj * 3 + 2];
            f4 av;
            float* avF = (float*)&av;
            #pragma unroll
            for (int r = 0; r < 4; ++r) {
                const int ii = i0 + r;
                const float dx = cjx - cS[ii * 3], dy = cjy - cS[ii * 3 + 1], dz = cjz - cS[ii * 3 + 2];
                avF[r] = __expf(-0.5f * (dx * dx + dy * dy + dz * dz));
            }
            As4[jj] = av;
        }
    }

    // ---- issue emb chunk1 reads early (latency hides under chunk0 compute) ----
    f4 ev1[16];
    #pragma unroll
    for (int i = 0; i < 16; ++i)
        ev1[i] = emb4[(size_t)(b * NN + (b_ + 16 * i)) * 32 + 16 + a_];    // chunk1: cf = 16 + a_

    // ---- recompute H1b: chunk 0 ----
    const int rg = tid >> 3, cg = tid & 7;
    f4 acc[8][4];
    #pragma unroll
    for (int r = 0; r < 8; ++r)
        #pragma unroll
        for (int q = 0; q < 4; ++q) acc[r][q] = (f4)ZERO4;

    const f4* __restrict__ Wb0 = (const f4*)W1bC0;
    #pragma unroll 4
    for (int kl = 0; kl < 64; ++kl) {
        const f4 e0 = *(const f4*)&embT[kl * 256 + 8 * rg];
        const f4 e1 = *(const f4*)&embT[kl * 256 + 8 * rg + 4];
        f4 w[4];
        #pragma unroll
        for (int q = 0; q < 4; ++q) w[q] = Wb0[kl * 32 + cg + 8 * q];
        #pragma unroll
        for (int q = 0; q < 4; ++q) {
            FMA4(acc[0][q], e0.x, w[q]);
            FMA4(acc[1][q], e0.y, w[q]);
            FMA4(acc[2][q], e0.z, w[q]);
            FMA4(acc[3][q], e0.w, w[q]);
            FMA4(acc[4][q], e1.x, w[q]);
            FMA4(acc[5][q], e1.y, w[q]);
            FMA4(acc[6][q], e1.z, w[q]);
            FMA4(acc[7][q], e1.w, w[q]);
        }
    }
    __syncthreads();                    // chunk0 embT reads complete

    // ---- transpose-write emb chunk1, then chunk 1 compute ----
    #pragma unroll
    for (int i = 0; i < 16; ++i) {
        const int row = b_ + 16 * i;
        embT[(4 * a_ + 0) * 256 + row] = ev1[i].x;
        embT[(4 * a_ + 1) * 256 + row] = ev1[i].y;
        embT[(4 * a_ + 2) * 256 + row] = ev1[i].z;
        embT[(4 * a_ + 3) * 256 + row] = ev1[i].w;
    }
    __syncthreads();

    const f4* __restrict__ Wb1 = (const f4*)W1bC1;
    #pragma unroll 4
    for (int kl = 0; kl < 64; ++kl) {
        const f4 e0 = *(const f4*)&embT[kl * 256 + 8 * rg];
        const f4 e1 = *(const f4*)&embT[kl * 256 + 8 * rg + 4];
        f4 w[4];
        #pragma unroll
        for (int q = 0; q < 4; ++q) w[q] = Wb1[kl * 32 + cg + 8 * q];
        #pragma unroll
        for (int q = 0; q < 4; ++q) {
            FMA4(acc[0][q], e0.x, w[q]);
            FMA4(acc[1][q], e0.y, w[q]);
            FMA4(acc[2][q], e0.z, w[q]);
            FMA4(acc[3][q], e0.w, w[q]);
            FMA4(acc[4][q], e1.x, w[q]);
            FMA4(acc[5][q], e1.y, w[q]);
            FMA4(acc[6][q], e1.z, w[q]);
            FMA4(acc[7][q], e1.w, w[q]);
        }
    }
    __syncthreads();                    // all BIG reads complete -> H1bL overlay

    // ---- write H1b into LDS [256][32] f4 ----
    f4* H1b4 = (f4*)BIG;
    #pragma unroll
    for (int r = 0; r < 8; ++r)
        #pragma unroll
        for (int q = 0; q < 4; ++q)
            H1b4[(8 * rg + r) * 32 + cg + 8 * q] = acc[r][q];
    __syncthreads();

    // ======== post-phase (v7 structure, 256-thread indexing) ========
    const int eq = tid & 31;            // f4-col of 128 e-cols
    const int js = tid >> 5;            // 0..7 : 32 j each; doubles as kh (16 k)

    const f4 pa0 = ((const f4*)paS)[0 * 32 + eq];
    const f4 pa1 = ((const f4*)paS)[1 * 32 + eq];
    const f4 pa2 = ((const f4*)paS)[2 * 32 + eq];
    const f4 pa3 = ((const f4*)paS)[3 * 32 + eq];

    // ---- j-phase ----
    f4 j0 = ZERO4, j1 = ZERO4, j2 = ZERO4, j3 = ZERO4, sA4 = ZERO4;
    #pragma unroll 8
    for (int t = 0; t < 32; ++t) {
        const int j = js * 32 + t;
        const f4 a = As4[j];
        const f4 v = H1b4[j * 32 + eq];
        sA4.x += a.x; sA4.y += a.y; sA4.z += a.z; sA4.w += a.w;
        FMA4R(j0, a.x, pa0, v);
        FMA4R(j1, a.y, pa1, v);
        FMA4R(j2, a.z, pa2, v);
        FMA4R(j3, a.w, pa3, v);
    }
    __syncthreads();                    // H1b reads done -> red overlay

    f4* red4 = (f4*)BIG;                // [js*4 + r][32] : 16 KB
    red4[(js * 4 + 0) * 32 + eq] = j0;
    red4[(js * 4 + 1) * 32 + eq] = j1;
    red4[(js * 4 + 2) * 32 + eq] = j2;
    red4[(js * 4 + 3) * 32 + eq] = j3;
    if (eq == 0) sAs4[js] = sA4;
    // prefetch G1 weights (16 k x own f4-col)
    f4 wv[16];
    {   const f4* __restrict__ W2g = (const f4*)mW2;
        #pragma unroll
        for (int t = 0; t < 16; ++t) wv[t] = W2g[(size_t)(js * 16 + t) * 32 + eq];
    }
    __syncthreads();

    // ---- R reduce ----
    const float* __restrict__ redF = (const float*)BIG;
    #pragma unroll
    for (int tt = 0; tt < 2; ++tt) {
        const int o = tt * 256 + tid;
        const int r = o >> 7, e = o & 127;
        float s = 0.f;
        #pragma unroll
        for (int q = 0; q < 8; ++q) s += redF[(q * 4 + r) * 128 + e];
        ((float*)R_T)[e * 4 + r] = s;
    }
    if (tid < 4) {
        const float* __restrict__ sF = (const float*)sAs4;
        float s = 0.f;
        #pragma unroll
        for (int q = 0; q < 8; ++q) s += sF[q * 4 + tid];
        sAtot[tid] = s;
    }
    __syncthreads();

    // ---- G1: agg partials = R @ mW2 ----
    {   f4 g0 = ZERO4, g1 = ZERO4, g2 = ZERO4, g3 = ZERO4;
        #pragma unroll
        for (int t = 0; t < 16; ++t) {
            const f4 rv = R_T[js * 16 + t];
            FMA4(g0, rv.x, wv[t]);
            FMA4(g1, rv.y, wv[t]);
            FMA4(g2, rv.z, wv[t]);
            FMA4(g3, rv.w, wv[t]);
        }
        red4[(js * 4 + 0) * 32 + eq] = g0;
        red4[(js * 4 + 1) * 32 + eq] = g1;
        red4[(js * 4 + 2) * 32 + eq] = g2;
        red4[(js * 4 + 3) * 32 + eq] = g3;
    }
    f4 wt0 = ZERO4, wt1 = ZERO4, wt2 = ZERO4;
    {   const f4* __restrict__ U1g = (const f4*)uW1;
        #pragma unroll
        for (int t = 0; t < 16; ++t) wv[t] = U1g[(size_t)(js * 16 + t) * 32 + eq];
        if (js == 7) {
            wt0 = U1g[(size_t)(DD + 0) * 32 + eq];
            wt1 = U1g[(size_t)(DD + 1) * 32 + eq];
            wt2 = U1g[(size_t)(DD + 2) * 32 + eq];
        }
    }
    __syncthreads();

    // ---- U assemble ----
    #pragma unroll
    for (int tt = 0; tt < 2; ++tt) {
        const int o = tt * 256 + tid;
        const int r = o >> 7, e = o & 127;
        float s = sAtot[r] * mb2[e];
        #pragma unroll
        for (int q = 0; q < 8; ++q) s += redF[(q * 4 + r) * 128 + e];
        ((float*)U_T)[e * 4 + r] = s;
    }
    if (tid < 12) {
        const int r = tid & 3, c = tid >> 2;
        ((float*)U_T)[(DD + c) * 4 + r] = cS[(i0 + r) * 3 + c];
    }
    __syncthreads();

    // ---- G2: hid partials = upd_in @ uW1 (js==7 adds 3 tail rows) ----
    {   f4 g0 = ZERO4, g1 = ZERO4, g2 = ZERO4, g3 = ZERO4;
        #pragma unroll
        for (int t = 0; t < 16; ++t) {
            const f4 uv = U_T[js * 16 + t];
            FMA4(g0, uv.x, wv[t]);
            FMA4(g1, uv.y, wv[t]);
            FMA4(g2, uv.z, wv[t]);
            FMA4(g3, uv.w, wv[t]);
        }
        if (js == 7) {
            const f4 uv0 = U_T[DD + 0], uv1 = U_T[DD + 1], uv2 = U_T[DD + 2];
            FMA4(g0, uv0.x, wt0); FMA4(g1, uv0.y, wt0); FMA4(g2, uv0.z, wt0); FMA4(g3, uv0.w, wt0);
            FMA4(g0, uv1.x, wt1); FMA4(g1, uv1.y, wt1); FMA4(g2, uv1.z, wt1); FMA4(g3, uv1.w, wt1);
            FMA4(g0, uv2.x, wt2); FMA4(g1, uv2.y, wt2); FMA4(g2, uv2.z, wt2); FMA4(g3, uv2.w, wt2);
        }
        red4[(js * 4 + 0) * 32 + eq] = g0;
        red4[(js * 4 + 1) * 32 + eq] = g1;
        red4[(js * 4 + 2) * 32 + eq] = g2;
        red4[(js * 4 + 3) * 32 + eq] = g3;
    }
    {   const f4* __restrict__ U2g = (const f4*)uW2;
        #pragma unroll
        for (int t = 0; t < 16; ++t) wv[t] = U2g[(size_t)(js * 16 + t) * 32 + eq];
    }
    __syncthreads();

    // ---- H: reduce + relu ----
    #pragma unroll
    for (int tt = 0; tt < 2; ++tt) {
        const int o = tt * 256 + tid;
        const int r = o >> 7, e = o & 127;
        float s = ub1[e];
        #pragma unroll
        for (int q = 0; q < 8; ++q) s += redF[(q * 4 + r) * 128 + e];
        ((float*)h_T)[e * 4 + r] = fmaxf(s, 0.f);
    }
    __syncthreads();

    // ---- G3: delta partials = hid @ uW2 ----
    {   f4 g0 = ZERO4, g1 = ZERO4, g2 = ZERO4, g3 = ZERO4;
        #pragma unroll
        for (int t = 0; t < 16; ++t) {
            const f4 hv = h_T[js * 16 + t];
            FMA4(g0, hv.x, wv[t]);
            FMA4(g1, hv.y, wv[t]);
            FMA4(g2, hv.z, wv[t]);
            FMA4(g3, hv.w, wv[t]);
        }
        red4[(js * 4 + 0) * 32 + eq] = g0;
        red4[(js * 4 + 1) * 32 + eq] = g1;
        red4[(js * 4 + 2) * 32 + eq] = g2;
        red4[(js * 4 + 3) * 32 + eq] = g3;
    }
    __syncthreads();

    // ---- final: reduce + residual ----
    #pragma unroll
    for (int tt = 0; tt < 2; ++tt) {
        const int o = tt * 256 + tid;
        const int r = o >> 7, e = o & 127;
        float s = ub2[e];
        #pragma unroll
        for (int q = 0; q < 8; ++q) s += redF[(q * 4 + r) * 128 + e];
        out[(size_t)(row0 + r) * DD + e] = emb[(size_t)(row0 + r) * DD + e] + s;
    }
}

extern "C" void kernel_launch(void* const* d_in, const int* in_sizes, int n_in,
                              void* d_out, int out_size, void* d_ws, size_t ws_size,
                              hipStream_t stream) {
    const float* emb    = (const float*)d_in[0];
    const float* coords = (const float*)d_in[1];
    const float* mW1    = (const float*)d_in[2];
    const float* mb1    = (const float*)d_in[3];
    const float* mW2    = (const float*)d_in[4];
    const float* mb2    = (const float*)d_in[5];
    const float* uW1    = (const float*)d_in[6];
    const float* ub1    = (const float*)d_in[7];
    const float* uW2    = (const float*)d_in[8];
    const float* ub2    = (const float*)d_in[9];
    float* out = (float*)d_out;

    // Single kernel; d_ws intentionally unused (no inter-kernel state).
    fused_gnn<<<dim3(256), dim3(256), 0, stream>>>(
        emb, coords, mW1, mb1, mW2, mb2, uW1, ub1, uW2, ub2, out);
}